// Round 15
// baseline (2723.548 us; speedup 1.0000x reference)
//
#include <hip/hip_runtime.h>
#include <cstdint>

typedef unsigned short ushort_t;
typedef __attribute__((ext_vector_type(8))) short short8;
typedef __attribute__((ext_vector_type(4))) float f32x4;
typedef unsigned long long u64;

#define T_STEPS 512
#define BATCH   64
#define IDIM    512
#define HIDDEN  1024
#define NWGP    256         // 8 row-groups (bid&7) x 32 col-slices (bid>>3)
#define BH      (BATCH*HIDDEN)   // 65536
// LDS (ushort idx): [0,32768) Wz slice, [32768,65536) Wh slice,
// [65536,73728) STG A-staging (4 waves x 2KB-ushort), [73728,77824) SCRR.
#define STG     65536
#define SCRR    73728

__device__ __forceinline__ ushort_t f2bf(float f) {
  unsigned int x = __float_as_uint(f);
  unsigned int r = (x + 0x7fffu + ((x >> 16) & 1u)) >> 16;
  return (ushort_t)r;
}
__device__ __forceinline__ float sigmoid_f(float x) { return 1.f / (1.f + __expf(-x)); }
__device__ __forceinline__ float tanh_f(float x)    { return 1.f - 2.f / (1.f + __expf(2.f * x)); }

#define WAITV(N) asm volatile("s_waitcnt vmcnt(" #N ")" ::: "memory")

// coherent global->LDS direct load, 16B/lane, aux=17 (sc0|sc1): bypass L1+L2,
// read at LLC (R4-proven). Dest is wave-uniform base + lane*16 (linear).
__device__ __forceinline__ void glds16(const ushort_t* g, ushort_t* l) {
  __builtin_amdgcn_global_load_lds(
      (const __attribute__((address_space(1))) void*)g,
      (__attribute__((address_space(3))) void*)l, 16, 0, 17);
}

// stage this wave's k-quarter: 4 x 1KB, no lane duplication (16KB/WG total)
#define STAGE4(SRC) do { \
  glds16((SRC),       &smem[stgw]); \
  glds16((SRC) + 64,  &smem[stgw + 512]); \
  glds16((SRC) + 128, &smem[stgw + 1024]); \
  glds16((SRC) + 192, &smem[stgw + 1536]); \
} while (0)

// K-step with SWAPPED operands (D[j,m]): lane owns 4 consecutive output cols
// for one batch row. B (weights) read before the vmcnt wait.
#define KSTEPG(J, VN, WOFF) do { \
  const int k0_ = kqbase + (J) * 32 + koff; \
  short8 b0_ = *(const short8*)&smem[(WOFF) + wb0 + (k0_ ^ sz0)]; \
  short8 b1_ = *(const short8*)&smem[(WOFF) + wb1 + (k0_ ^ sz1)]; \
  WAITV(VN); \
  __builtin_amdgcn_sched_barrier(0); \
  short8 a_ = *(const short8*)&smem[abase + ((J) >> 1) * 512 + (axq ^ (((J) & 1) * 32))]; \
  acc0 = __builtin_amdgcn_mfma_f32_16x16x32_bf16(b0_, a_, acc0, 0, 0, 0); \
  acc1 = __builtin_amdgcn_mfma_f32_16x16x32_bf16(b1_, a_, acc1, 0, 0, 0); \
} while (0)

#define MATVEC8G(WOFF) do { \
  KSTEPG(0,3,WOFF); KSTEPG(1,3,WOFF); KSTEPG(2,2,WOFF); KSTEPG(3,2,WOFF); \
  KSTEPG(4,1,WOFF); KSTEPG(5,1,WOFF); KSTEPG(6,0,WOFF); KSTEPG(7,0,WOFF); \
} while (0)

// per-group barrier (32 WGs): tid0 polls group counter, broadcast, then all
// waves drain stale VMEM so the glds vmcnt ladder is exact.
#define POLL_GRP(TGT) do { \
  if (tid == 0) { \
    while (__hip_atomic_load(gctr, __ATOMIC_RELAXED, __HIP_MEMORY_SCOPE_AGENT) < (TGT)) \
      __builtin_amdgcn_s_sleep(1); \
  } \
  __syncthreads(); \
  WAITV(0); \
  __builtin_amdgcn_sched_barrier(0); \
} while (0)

// ---------------- weight conversion: f32 -> bf16, split h-part / x-part ----
__global__ __launch_bounds__(256) void convert_weights(
    const float* __restrict__ Wz, const float* __restrict__ Wh,
    ushort_t* __restrict__ Wzh, ushort_t* __restrict__ Wzx,
    ushort_t* __restrict__ Whh, ushort_t* __restrict__ Whx)
{
  int j = blockIdx.x;
  const float* W = blockIdx.y ? Wh : Wz;
  ushort_t* Bh = blockIdx.y ? Whh : Wzh;
  ushort_t* Bx = blockIdx.y ? Whx : Wzx;
  const float* row = W + (size_t)j * (HIDDEN + IDIM);
  for (int c = threadIdx.x; c < HIDDEN + IDIM; c += 256) {
    ushort_t v = f2bf(row[c]);
    if (c < HIDDEN) Bh[(size_t)j * HIDDEN + c] = v;
    else            Bx[(size_t)j * IDIM + (c - HIDDEN)] = v;
  }
}

// ---------------- phase 1: fused Gxz+Gxh GEMM, 64x128 tiles ----------------
__global__ __launch_bounds__(256) void gx_gemm2(
    const float* __restrict__ x,
    const ushort_t* __restrict__ Wzx, const ushort_t* __restrict__ Whx,
    const float* __restrict__ bz, const float* __restrict__ bh,
    float* __restrict__ outZ, float* __restrict__ outR)
{
  const int m0 = blockIdx.x * 64;
  const int n0 = blockIdx.y * 128;
  __shared__ ushort_t As[64 * 40];
  __shared__ ushort_t Bzs[128 * 40];
  __shared__ ushort_t Bhs[128 * 40];
  const int tid = threadIdx.x;
  const int lane = tid & 63, w4 = tid >> 6;
  const int li = lane & 15, q4 = lane >> 4;
  const int row = tid >> 2, q = tid & 3;
  f32x4 accz[8], acch[8];
  #pragma unroll
  for (int c = 0; c < 8; ++c) { accz[c] = (f32x4){0,0,0,0}; acch[c] = (f32x4){0,0,0,0}; }
  for (int kk = 0; kk < IDIM; kk += 32) {
    const float* xs = &x[(size_t)(m0 + row) * IDIM + kk + q * 8];
    float4 f0 = *(const float4*)xs;
    float4 f1 = *(const float4*)(xs + 4);
    short8 av;
    av[0]=f2bf(f0.x); av[1]=f2bf(f0.y); av[2]=f2bf(f0.z); av[3]=f2bf(f0.w);
    av[4]=f2bf(f1.x); av[5]=f2bf(f1.y); av[6]=f2bf(f1.z); av[7]=f2bf(f1.w);
    short8 bz0 = *(const short8*)&Wzx[(size_t)(n0 + row) * IDIM + kk + q * 8];
    short8 bz1 = *(const short8*)&Wzx[(size_t)(n0 + 64 + row) * IDIM + kk + q * 8];
    short8 bh0 = *(const short8*)&Whx[(size_t)(n0 + row) * IDIM + kk + q * 8];
    short8 bh1 = *(const short8*)&Whx[(size_t)(n0 + 64 + row) * IDIM + kk + q * 8];
    __syncthreads();
    *(short8*)&As[row * 40 + q * 8]         = av;
    *(short8*)&Bzs[row * 40 + q * 8]        = bz0;
    *(short8*)&Bzs[(64 + row) * 40 + q * 8] = bz1;
    *(short8*)&Bhs[row * 40 + q * 8]        = bh0;
    *(short8*)&Bhs[(64 + row) * 40 + q * 8] = bh1;
    __syncthreads();
    short8 af = *(const short8*)&As[(w4 * 16 + li) * 40 + q4 * 8];
    #pragma unroll
    for (int c = 0; c < 8; ++c) {
      short8 bzf = *(const short8*)&Bzs[(c * 16 + li) * 40 + q4 * 8];
      short8 bhf = *(const short8*)&Bhs[(c * 16 + li) * 40 + q4 * 8];
      accz[c] = __builtin_amdgcn_mfma_f32_16x16x32_bf16(af, bzf, accz[c], 0, 0, 0);
      acch[c] = __builtin_amdgcn_mfma_f32_16x16x32_bf16(af, bhf, acch[c], 0, 0, 0);
    }
  }
  #pragma unroll
  for (int c = 0; c < 8; ++c) {
    int j = n0 + c * 16 + li;
    float bzv = bz[j], bhv = bh[j];
    #pragma unroll
    for (int r = 0; r < 4; ++r) {
      int m = m0 + w4 * 16 + q4 * 4 + r;
      outZ[(size_t)m * HIDDEN + j] = accz[c][r] + bzv;
      outR[(size_t)m * HIDDEN + j] = acch[c][r] + bhv;
    }
  }
}

// ---------------- persistent recurrent kernel ------------------------------
// 8 independent row-groups (8 batch rows, grp=bid&7) x 32 col-slices. R13
// protocol (LLC sc1). New: next-step gz/gh prefetch moved to the phase-B tail
// behind WAITV(2) (in-order vmcnt: waits exactly the h-store ack, leaves the
// 2 HBM prefetch loads in flight for a full phase -> POLL_A never stalls on
// them).
__global__ __launch_bounds__(256) void gru_persist(
    const ushort_t* __restrict__ Wzh, const ushort_t* __restrict__ Whh,
    float* __restrict__ H, float* __restrict__ Z, float* __restrict__ R,
    u64* __restrict__ h_buf, u64* __restrict__ ghb, int* __restrict__ ctrs)
{
  extern __shared__ ushort_t smem[];
  const int tid = threadIdx.x;
  const int lane = tid & 63, wv = tid >> 6;
  const int grp = blockIdx.x & 7, slot = blockIdx.x >> 3;
  const int rbase = grp * 8;
  const int jbase = slot * 32;
  int* gctr = ctrs + grp * 32;           // 128B-spaced group counters
  const ushort_t* hgu = (const ushort_t*)h_buf;
  const ushort_t* ggu = (const ushort_t*)ghb;

  // stage weight slices (row-XOR swizzle k ^= (row&7)<<3)
  for (int c = tid; c < 32 * 128; c += 256) {
    int row = c >> 7, k8 = (c & 127) * 8;
    int dst = row * 1024 + (k8 ^ ((row & 7) << 3));
    *(short8*)&smem[dst]         = *(const short8*)&Wzh[(size_t)(jbase + row) * 1024 + k8];
    *(short8*)&smem[32768 + dst] = *(const short8*)&Whh[(size_t)(jbase + row) * 1024 + k8];
  }
  __syncthreads();   // weights ready (h0 + ctrs zeroed by host memset)

  // H[0] = 0 for this WG's 8x32 block (background)
  if (tid < 64) {
    float4 z4 = {0.f, 0.f, 0.f, 0.f};
    *(float4*)&H[(size_t)(rbase + (tid >> 3)) * 1024 + jbase + (tid & 7) * 4] = z4;
  }

  // wave decomposition: wv = k-quarter; epilogue on waves 0,1
  const int li = lane & 15, q4 = lane >> 4;
  const int kqbase = wv * 256;
  const int koff = q4 * 8;
  const int wb0 = li * 1024,     wb1 = (16 + li) * 1024;
  const int sz0 = (li & 7) << 3, sz1 = ((16 + li) & 7) << 3;
  const int srow = lane >> 3, schk = (lane & 7) ^ srow;
  const ushort_t* srcAh = hgu + (size_t)(rbase + srow) * 1024 + kqbase + schk * 8;
  const ushort_t* srcAg = ggu + (size_t)(rbase + srow) * 1024 + kqbase + schk * 8;
  const int stgw = STG + wv * 2048;
  const int abase = stgw + (li & 7) * 64;
  const int axq = (q4 ^ (li & 7)) * 8;
  const bool epi = (wv < 2) && (li < 8);
  const int erow = rbase + li;
  const int ecol = jbase + (wv & 1) * 16 + q4 * 4;
  const int gidx = (erow * 1024 + ecol) >> 2;
  const int rr0 = SCRR + ((0 * 4 + wv) * 64 + lane) * 8;
  const int rr1 = SCRR + ((1 * 4 + wv) * 64 + lane) * 8;
  const int rrc = SCRR + ((wv & 1) * 4 * 64 + lane) * 8;

  float hreg[4] = {0.f, 0.f, 0.f, 0.f};
  float g[4], hn[4], gz[4], gh[4];

  // initial prefetch (t=0); drained by POLL_GRP(0)'s trailing WAITV(0)
  if (epi) {
    f32x4 z4 = *(const f32x4*)&Z[(size_t)erow * 1024 + ecol];
    f32x4 r4 = *(const f32x4*)&R[(size_t)erow * 1024 + ecol];
    #pragma unroll
    for (int r = 0; r < 4; ++r) { gz[r] = z4[r]; gh[r] = r4[r]; }
  }

  for (int t = 0; t < T_STEPS; ++t) {
    const size_t zoff = (size_t)t * BH;

    // ---- phase A: z-gate -------------------------------------------------
    POLL_GRP(64 * t);                 // group finished h(t) stores

    f32x4 acc0 = {0, 0, 0, 0}, acc1 = {0, 0, 0, 0};
    STAGE4(srcAh);
    MATVEC8G(0);

    *(f32x4*)&smem[rr0] = acc0;
    *(f32x4*)&smem[rr1] = acc1;
    __syncthreads();
    if (epi) {
      f32x4 s = *(const f32x4*)&smem[rrc];
      #pragma unroll
      for (int q = 1; q < 4; ++q) {
        f32x4 o = *(const f32x4*)&smem[rrc + q * 64 * 8];
        #pragma unroll
        for (int r = 0; r < 4; ++r) s[r] += o[r];
      }
      #pragma unroll
      for (int r = 0; r < 4; ++r) g[r] = sigmoid_f(s[r] + gz[r]);
      u64 v = (u64)f2bf(g[0] * hreg[0])
            | ((u64)f2bf(g[1] * hreg[1]) << 16)
            | ((u64)f2bf(g[2] * hreg[2]) << 32)
            | ((u64)f2bf(g[3] * hreg[3]) << 48);
      __hip_atomic_store(ghb + gidx, v, __ATOMIC_RELAXED, __HIP_MEMORY_SCOPE_AGENT);
    }
    WAITV(0);                          // g*h stores acked at LLC
    __syncthreads();
    if (tid == 0)
      __hip_atomic_fetch_add(gctr, 1, __ATOMIC_RELAXED, __HIP_MEMORY_SCOPE_AGENT);

    // ---- phase B: candidate ---------------------------------------------
    POLL_GRP(64 * t + 32);            // group finished g*h stores

    acc0 = (f32x4){0, 0, 0, 0}; acc1 = (f32x4){0, 0, 0, 0};
    STAGE4(srcAg);
    MATVEC8G(32768);

    *(f32x4*)&smem[rr0] = acc0;
    *(f32x4*)&smem[rr1] = acc1;
    __syncthreads();
    if (epi) {
      f32x4 s = *(const f32x4*)&smem[rrc];
      #pragma unroll
      for (int q = 1; q < 4; ++q) {
        f32x4 o = *(const f32x4*)&smem[rrc + q * 64 * 8];
        #pragma unroll
        for (int r = 0; r < 4; ++r) s[r] += o[r];
      }
      #pragma unroll
      for (int r = 0; r < 4; ++r) {
        float cand = tanh_f(s[r] + gh[r]);
        hn[r] = (1.f - g[r]) * hreg[r] + g[r] * cand;
        hreg[r] = hn[r];
      }
      u64 v = (u64)f2bf(hn[0])
            | ((u64)f2bf(hn[1]) << 16)
            | ((u64)f2bf(hn[2]) << 32)
            | ((u64)f2bf(hn[3]) << 48);
      __hip_atomic_store(h_buf + gidx, v, __ATOMIC_RELAXED, __HIP_MEMORY_SCOPE_AGENT);
      // next-step gz/gh prefetch AFTER the store (in-order vmcnt): index
      // clamped to keep 3-outstanding invariant; values unused at t=511.
      const size_t pnoff = (size_t)((t + 1) & (T_STEPS - 1)) * BH;
      f32x4 z4 = *(const f32x4*)&Z[pnoff + (size_t)erow * 1024 + ecol];
      f32x4 r4 = *(const f32x4*)&R[pnoff + (size_t)erow * 1024 + ecol];
      #pragma unroll
      for (int r = 0; r < 4; ++r) { gz[r] = z4[r]; gh[r] = r4[r]; }
    }
    WAITV(2);                          // h-store acked; prefetches in flight
    __syncthreads();
    if (tid == 0)
      __hip_atomic_fetch_add(gctr, 1, __ATOMIC_RELAXED, __HIP_MEMORY_SCOPE_AGENT);

    // bulk outputs (drain in background during next poll) — float4 stores
    if (epi) {
      const size_t hoff = (size_t)(t + 1) * BH;
      const size_t rowo = (size_t)erow * 1024 + ecol;
      float4 gv = {g[0], g[1], g[2], g[3]};
      float4 hv = {hn[0], hn[1], hn[2], hn[3]};
      *(float4*)&Z[zoff + rowo] = gv;
      *(float4*)&R[zoff + rowo] = gv;
      *(float4*)&H[hoff + rowo] = hv;
    }
  }
}

// ---------------- host launcher -------------------------------------------
extern "C" void kernel_launch(void* const* d_in, const int* in_sizes, int n_in,
                              void* d_out, int out_size, void* d_ws, size_t ws_size,
                              hipStream_t stream) {
  (void)in_sizes; (void)n_in; (void)out_size; (void)ws_size;
  const float* x  = (const float*)d_in[0];
  const float* Wz = (const float*)d_in[1];
  const float* bz = (const float*)d_in[2];
  const float* Wh = (const float*)d_in[3];
  const float* bh = (const float*)d_in[4];

  float* H = (float*)d_out;
  float* Z = H + (size_t)(T_STEPS + 1) * BH;
  float* R = Z + (size_t)T_STEPS * BH;

  char* ws = (char*)d_ws;
  int*      ctrs  = (int*)ws;                                   // 8 group ctrs, 128B apart
  u64*      h_buf = (u64*)(ws + 16384);                         // 128 KB linear bf16
  u64*      ghb   = (u64*)(ws + 16384 + 131072);                // 128 KB linear bf16
  ushort_t* Wzh   = (ushort_t*)(ws + 16384 + 2 * 131072);       // 2 MB
  ushort_t* Whh   = Wzh + (size_t)HIDDEN * HIDDEN;              // 2 MB
  ushort_t* Wzx   = Whh + (size_t)HIDDEN * HIDDEN;              // 1 MB
  ushort_t* Whx   = Wzx + (size_t)HIDDEN * IDIM;                // 1 MB

  hipFuncSetAttribute((const void*)gru_persist,
                      hipFuncAttributeMaxDynamicSharedMemorySize, 155648);

  hipMemsetAsync(ctrs, 0, 16384, stream);
  hipMemsetAsync(h_buf, 0, 131072, stream);   // h0 = 0 (kernel-boundary visible)
  convert_weights<<<dim3(HIDDEN, 2), 256, 0, stream>>>(Wz, Wh, Wzh, Wzx, Whh, Whx);
  gx_gemm2<<<dim3(T_STEPS * BATCH / 64, HIDDEN / 128), 256, 0, stream>>>(
      x, Wzx, Whx, bz, bh, Z, R);
  gru_persist<<<NWGP, 256, 155648, stream>>>(Wzh, Whh, H, Z, R, h_buf, ghb, ctrs);
}

// Round 16
// 2322.027 us; speedup vs baseline: 1.1729x; 1.1729x over previous
//
#include <hip/hip_runtime.h>
#include <cstdint>

typedef unsigned short ushort_t;
typedef __attribute__((ext_vector_type(8))) short short8;
typedef __attribute__((ext_vector_type(4))) float f32x4;
typedef unsigned long long u64;

#define T_STEPS 512
#define BATCH   64
#define IDIM    512
#define HIDDEN  1024
#define NWGP    256         // 8 row-groups (bid&7) x 32 col-slices (bid>>3)
#define BH      (BATCH*HIDDEN)   // 65536
// LDS (ushort idx): [0,32768) Wz slice, [32768,65536) Wh slice,
// [65536,73728) STG A-staging (4 waves x 2KB-ushort), [73728,77824) SCRR.
#define STG     65536
#define SCRR    73728

__device__ __forceinline__ ushort_t f2bf(float f) {
  unsigned int x = __float_as_uint(f);
  unsigned int r = (x + 0x7fffu + ((x >> 16) & 1u)) >> 16;
  return (ushort_t)r;
}
__device__ __forceinline__ float sigmoid_f(float x) { return 1.f / (1.f + __expf(-x)); }
__device__ __forceinline__ float tanh_f(float x)    { return 1.f - 2.f / (1.f + __expf(2.f * x)); }

#define WAITV(N) asm volatile("s_waitcnt vmcnt(" #N ")" ::: "memory")

// coherent global->LDS direct load, 16B/lane, aux=17 (sc0|sc1): bypass L1+L2,
// read at LLC (R4-proven). Dest is wave-uniform base + lane*16 (linear).
__device__ __forceinline__ void glds16(const ushort_t* g, ushort_t* l) {
  __builtin_amdgcn_global_load_lds(
      (const __attribute__((address_space(1))) void*)g,
      (__attribute__((address_space(3))) void*)l, 16, 0, 17);
}

// stage this wave's k-quarter: 4 x 1KB, no lane duplication (16KB/WG total)
#define STAGE4(SRC) do { \
  glds16((SRC),       &smem[stgw]); \
  glds16((SRC) + 64,  &smem[stgw + 512]); \
  glds16((SRC) + 128, &smem[stgw + 1024]); \
  glds16((SRC) + 192, &smem[stgw + 1536]); \
} while (0)

// K-step with SWAPPED operands (D[j,m]): lane owns 4 consecutive output cols
// for one batch row. B (weights) read before the vmcnt wait.
#define KSTEPG(J, VN, WOFF) do { \
  const int k0_ = kqbase + (J) * 32 + koff; \
  short8 b0_ = *(const short8*)&smem[(WOFF) + wb0 + (k0_ ^ sz0)]; \
  short8 b1_ = *(const short8*)&smem[(WOFF) + wb1 + (k0_ ^ sz1)]; \
  WAITV(VN); \
  __builtin_amdgcn_sched_barrier(0); \
  short8 a_ = *(const short8*)&smem[abase + ((J) >> 1) * 512 + (axq ^ (((J) & 1) * 32))]; \
  acc0 = __builtin_amdgcn_mfma_f32_16x16x32_bf16(b0_, a_, acc0, 0, 0, 0); \
  acc1 = __builtin_amdgcn_mfma_f32_16x16x32_bf16(b1_, a_, acc1, 0, 0, 0); \
} while (0)

#define MATVEC8G(WOFF) do { \
  KSTEPG(0,3,WOFF); KSTEPG(1,3,WOFF); KSTEPG(2,2,WOFF); KSTEPG(3,2,WOFF); \
  KSTEPG(4,1,WOFF); KSTEPG(5,1,WOFF); KSTEPG(6,0,WOFF); KSTEPG(7,0,WOFF); \
} while (0)

// per-group barrier (32 WGs): tid0 polls group counter, broadcast, then all
// waves drain stale VMEM so the glds vmcnt ladder is exact.
#define POLL_GRP(TGT) do { \
  if (tid == 0) { \
    while (__hip_atomic_load(gctr, __ATOMIC_RELAXED, __HIP_MEMORY_SCOPE_AGENT) < (TGT)) \
      __builtin_amdgcn_s_sleep(1); \
  } \
  __syncthreads(); \
  WAITV(0); \
  __builtin_amdgcn_sched_barrier(0); \
} while (0)

// ---------------- weight conversion: f32 -> bf16, split h-part / x-part ----
__global__ __launch_bounds__(256) void convert_weights(
    const float* __restrict__ Wz, const float* __restrict__ Wh,
    ushort_t* __restrict__ Wzh, ushort_t* __restrict__ Wzx,
    ushort_t* __restrict__ Whh, ushort_t* __restrict__ Whx)
{
  int j = blockIdx.x;
  const float* W = blockIdx.y ? Wh : Wz;
  ushort_t* Bh = blockIdx.y ? Whh : Wzh;
  ushort_t* Bx = blockIdx.y ? Whx : Wzx;
  const float* row = W + (size_t)j * (HIDDEN + IDIM);
  for (int c = threadIdx.x; c < HIDDEN + IDIM; c += 256) {
    ushort_t v = f2bf(row[c]);
    if (c < HIDDEN) Bh[(size_t)j * HIDDEN + c] = v;
    else            Bx[(size_t)j * IDIM + (c - HIDDEN)] = v;
  }
}

// ---------------- phase 1: fused Gxz+Gxh GEMM, 64x128 tiles ----------------
__global__ __launch_bounds__(256) void gx_gemm2(
    const float* __restrict__ x,
    const ushort_t* __restrict__ Wzx, const ushort_t* __restrict__ Whx,
    const float* __restrict__ bz, const float* __restrict__ bh,
    float* __restrict__ outZ, float* __restrict__ outR)
{
  const int m0 = blockIdx.x * 64;
  const int n0 = blockIdx.y * 128;
  __shared__ ushort_t As[64 * 40];
  __shared__ ushort_t Bzs[128 * 40];
  __shared__ ushort_t Bhs[128 * 40];
  const int tid = threadIdx.x;
  const int lane = tid & 63, w4 = tid >> 6;
  const int li = lane & 15, q4 = lane >> 4;
  const int row = tid >> 2, q = tid & 3;
  f32x4 accz[8], acch[8];
  #pragma unroll
  for (int c = 0; c < 8; ++c) { accz[c] = (f32x4){0,0,0,0}; acch[c] = (f32x4){0,0,0,0}; }
  for (int kk = 0; kk < IDIM; kk += 32) {
    const float* xs = &x[(size_t)(m0 + row) * IDIM + kk + q * 8];
    float4 f0 = *(const float4*)xs;
    float4 f1 = *(const float4*)(xs + 4);
    short8 av;
    av[0]=f2bf(f0.x); av[1]=f2bf(f0.y); av[2]=f2bf(f0.z); av[3]=f2bf(f0.w);
    av[4]=f2bf(f1.x); av[5]=f2bf(f1.y); av[6]=f2bf(f1.z); av[7]=f2bf(f1.w);
    short8 bz0 = *(const short8*)&Wzx[(size_t)(n0 + row) * IDIM + kk + q * 8];
    short8 bz1 = *(const short8*)&Wzx[(size_t)(n0 + 64 + row) * IDIM + kk + q * 8];
    short8 bh0 = *(const short8*)&Whx[(size_t)(n0 + row) * IDIM + kk + q * 8];
    short8 bh1 = *(const short8*)&Whx[(size_t)(n0 + 64 + row) * IDIM + kk + q * 8];
    __syncthreads();
    *(short8*)&As[row * 40 + q * 8]         = av;
    *(short8*)&Bzs[row * 40 + q * 8]        = bz0;
    *(short8*)&Bzs[(64 + row) * 40 + q * 8] = bz1;
    *(short8*)&Bhs[row * 40 + q * 8]        = bh0;
    *(short8*)&Bhs[(64 + row) * 40 + q * 8] = bh1;
    __syncthreads();
    short8 af = *(const short8*)&As[(w4 * 16 + li) * 40 + q4 * 8];
    #pragma unroll
    for (int c = 0; c < 8; ++c) {
      short8 bzf = *(const short8*)&Bzs[(c * 16 + li) * 40 + q4 * 8];
      short8 bhf = *(const short8*)&Bhs[(c * 16 + li) * 40 + q4 * 8];
      accz[c] = __builtin_amdgcn_mfma_f32_16x16x32_bf16(af, bzf, accz[c], 0, 0, 0);
      acch[c] = __builtin_amdgcn_mfma_f32_16x16x32_bf16(af, bhf, acch[c], 0, 0, 0);
    }
  }
  #pragma unroll
  for (int c = 0; c < 8; ++c) {
    int j = n0 + c * 16 + li;
    float bzv = bz[j], bhv = bh[j];
    #pragma unroll
    for (int r = 0; r < 4; ++r) {
      int m = m0 + w4 * 16 + q4 * 4 + r;
      outZ[(size_t)m * HIDDEN + j] = accz[c][r] + bzv;
      outR[(size_t)m * HIDDEN + j] = acch[c][r] + bhv;
    }
  }
}

// ---------------- persistent recurrent kernel (R13, proven) ----------------
// 8 independent row-groups (8 batch rows, grp=bid&7) x 32 col-slices.
// Loop-top gz/gh prefetch (drained during POLL_A detect); NOTHING slow sits
// between the release store-ack and the arrive fetch_add (R15 lesson).
__global__ __launch_bounds__(256) void gru_persist(
    const ushort_t* __restrict__ Wzh, const ushort_t* __restrict__ Whh,
    float* __restrict__ H, float* __restrict__ Z, float* __restrict__ R,
    u64* __restrict__ h_buf, u64* __restrict__ ghb, int* __restrict__ ctrs)
{
  extern __shared__ ushort_t smem[];
  const int tid = threadIdx.x;
  const int lane = tid & 63, wv = tid >> 6;
  const int grp = blockIdx.x & 7, slot = blockIdx.x >> 3;
  const int rbase = grp * 8;             // batch-row block (8 rows)
  const int jbase = slot * 32;           // output-column block
  int* gctr = ctrs + grp * 32;           // 128B-spaced group counters
  const ushort_t* hgu = (const ushort_t*)h_buf;
  const ushort_t* ggu = (const ushort_t*)ghb;

  // stage weight slices (row-XOR swizzle k ^= (row&7)<<3)
  for (int c = tid; c < 32 * 128; c += 256) {
    int row = c >> 7, k8 = (c & 127) * 8;
    int dst = row * 1024 + (k8 ^ ((row & 7) << 3));
    *(short8*)&smem[dst]         = *(const short8*)&Wzh[(size_t)(jbase + row) * 1024 + k8];
    *(short8*)&smem[32768 + dst] = *(const short8*)&Whh[(size_t)(jbase + row) * 1024 + k8];
  }
  __syncthreads();   // weights ready (h0 + ctrs zeroed by host memset)

  // H[0] = 0 for this WG's 8x32 block (background)
  if (tid < 64) {
    float4 z4 = {0.f, 0.f, 0.f, 0.f};
    *(float4*)&H[(size_t)(rbase + (tid >> 3)) * 1024 + jbase + (tid & 7) * 4] = z4;
  }

  // wave decomposition: wv = k-quarter; epilogue on waves 0,1
  const int li = lane & 15, q4 = lane >> 4;
  const int kqbase = wv * 256;
  const int koff = q4 * 8;
  const int wb0 = li * 1024,     wb1 = (16 + li) * 1024;
  const int sz0 = (li & 7) << 3, sz1 = ((16 + li) & 7) << 3;
  const int srow = lane >> 3, schk = (lane & 7) ^ srow;
  const ushort_t* srcAh = hgu + (size_t)(rbase + srow) * 1024 + kqbase + schk * 8;
  const ushort_t* srcAg = ggu + (size_t)(rbase + srow) * 1024 + kqbase + schk * 8;
  const int stgw = STG + wv * 2048;
  const int abase = stgw + (li & 7) * 64;
  const int axq = (q4 ^ (li & 7)) * 8;
  const bool epi = (wv < 2) && (li < 8);
  const int erow = rbase + li;
  const int ecol = jbase + (wv & 1) * 16 + q4 * 4;
  const int gidx = (erow * 1024 + ecol) >> 2;
  const int rr0 = SCRR + ((0 * 4 + wv) * 64 + lane) * 8;
  const int rr1 = SCRR + ((1 * 4 + wv) * 64 + lane) * 8;
  const int rrc = SCRR + ((wv & 1) * 4 * 64 + lane) * 8;

  float hreg[4] = {0.f, 0.f, 0.f, 0.f};
  float g[4], hn[4], gz[4], gh[4];

  for (int t = 0; t < T_STEPS; ++t) {
    const size_t zoff = (size_t)t * BH;

    // prefetch BOTH gate inputs before POLL-A (drain window = detect time)
    if (epi) {
      f32x4 z4 = *(const f32x4*)&Z[zoff + (size_t)erow * 1024 + ecol];
      f32x4 r4 = *(const f32x4*)&R[zoff + (size_t)erow * 1024 + ecol];
      #pragma unroll
      for (int r = 0; r < 4; ++r) { gz[r] = z4[r]; gh[r] = r4[r]; }
    }

    // ---- phase A: z-gate -------------------------------------------------
    POLL_GRP(64 * t);                 // group finished h(t) stores

    f32x4 acc0 = {0, 0, 0, 0}, acc1 = {0, 0, 0, 0};
    STAGE4(srcAh);
    MATVEC8G(0);

    *(f32x4*)&smem[rr0] = acc0;
    *(f32x4*)&smem[rr1] = acc1;
    __syncthreads();
    if (epi) {
      f32x4 s = *(const f32x4*)&smem[rrc];
      #pragma unroll
      for (int q = 1; q < 4; ++q) {
        f32x4 o = *(const f32x4*)&smem[rrc + q * 64 * 8];
        #pragma unroll
        for (int r = 0; r < 4; ++r) s[r] += o[r];
      }
      #pragma unroll
      for (int r = 0; r < 4; ++r) g[r] = sigmoid_f(s[r] + gz[r]);
      u64 v = (u64)f2bf(g[0] * hreg[0])
            | ((u64)f2bf(g[1] * hreg[1]) << 16)
            | ((u64)f2bf(g[2] * hreg[2]) << 32)
            | ((u64)f2bf(g[3] * hreg[3]) << 48);
      __hip_atomic_store(ghb + gidx, v, __ATOMIC_RELAXED, __HIP_MEMORY_SCOPE_AGENT);
    }
    WAITV(0);                          // g*h stores acked at LLC
    __syncthreads();
    if (tid == 0)
      __hip_atomic_fetch_add(gctr, 1, __ATOMIC_RELAXED, __HIP_MEMORY_SCOPE_AGENT);

    // ---- phase B: candidate ---------------------------------------------
    POLL_GRP(64 * t + 32);            // group finished g*h stores

    acc0 = (f32x4){0, 0, 0, 0}; acc1 = (f32x4){0, 0, 0, 0};
    STAGE4(srcAg);
    MATVEC8G(32768);

    *(f32x4*)&smem[rr0] = acc0;
    *(f32x4*)&smem[rr1] = acc1;
    __syncthreads();
    if (epi) {
      f32x4 s = *(const f32x4*)&smem[rrc];
      #pragma unroll
      for (int q = 1; q < 4; ++q) {
        f32x4 o = *(const f32x4*)&smem[rrc + q * 64 * 8];
        #pragma unroll
        for (int r = 0; r < 4; ++r) s[r] += o[r];
      }
      #pragma unroll
      for (int r = 0; r < 4; ++r) {
        float cand = tanh_f(s[r] + gh[r]);
        hn[r] = (1.f - g[r]) * hreg[r] + g[r] * cand;
        hreg[r] = hn[r];
      }
      u64 v = (u64)f2bf(hn[0])
            | ((u64)f2bf(hn[1]) << 16)
            | ((u64)f2bf(hn[2]) << 32)
            | ((u64)f2bf(hn[3]) << 48);
      __hip_atomic_store(h_buf + gidx, v, __ATOMIC_RELAXED, __HIP_MEMORY_SCOPE_AGENT);
    }
    WAITV(0);                          // h stores acked at LLC
    __syncthreads();
    if (tid == 0)
      __hip_atomic_fetch_add(gctr, 1, __ATOMIC_RELAXED, __HIP_MEMORY_SCOPE_AGENT);

    // bulk outputs (drain in background during next poll) — float4 stores
    if (epi) {
      const size_t hoff = (size_t)(t + 1) * BH;
      const size_t rowo = (size_t)erow * 1024 + ecol;
      float4 gv = {g[0], g[1], g[2], g[3]};
      float4 hv = {hn[0], hn[1], hn[2], hn[3]};
      *(float4*)&Z[zoff + rowo] = gv;
      *(float4*)&R[zoff + rowo] = gv;
      *(float4*)&H[hoff + rowo] = hv;
    }
  }
}

// ---------------- host launcher -------------------------------------------
extern "C" void kernel_launch(void* const* d_in, const int* in_sizes, int n_in,
                              void* d_out, int out_size, void* d_ws, size_t ws_size,
                              hipStream_t stream) {
  (void)in_sizes; (void)n_in; (void)out_size; (void)ws_size;
  const float* x  = (const float*)d_in[0];
  const float* Wz = (const float*)d_in[1];
  const float* bz = (const float*)d_in[2];
  const float* Wh = (const float*)d_in[3];
  const float* bh = (const float*)d_in[4];

  float* H = (float*)d_out;
  float* Z = H + (size_t)(T_STEPS + 1) * BH;
  float* R = Z + (size_t)T_STEPS * BH;

  char* ws = (char*)d_ws;
  int*      ctrs  = (int*)ws;                                   // 8 group ctrs, 128B apart
  u64*      h_buf = (u64*)(ws + 16384);                         // 128 KB linear bf16
  u64*      ghb   = (u64*)(ws + 16384 + 131072);                // 128 KB linear bf16
  ushort_t* Wzh   = (ushort_t*)(ws + 16384 + 2 * 131072);       // 2 MB
  ushort_t* Whh   = Wzh + (size_t)HIDDEN * HIDDEN;              // 2 MB
  ushort_t* Wzx   = Whh + (size_t)HIDDEN * HIDDEN;              // 1 MB
  ushort_t* Whx   = Wzx + (size_t)HIDDEN * IDIM;                // 1 MB

  hipFuncSetAttribute((const void*)gru_persist,
                      hipFuncAttributeMaxDynamicSharedMemorySize, 155648);

  hipMemsetAsync(ctrs, 0, 16384, stream);
  hipMemsetAsync(h_buf, 0, 131072, stream);   // h0 = 0 (kernel-boundary visible)
  convert_weights<<<dim3(HIDDEN, 2), 256, 0, stream>>>(Wz, Wh, Wzh, Wzx, Whh, Whx);
  gx_gemm2<<<dim3(T_STEPS * BATCH / 64, HIDDEN / 128), 256, 0, stream>>>(
      x, Wzx, Whx, bz, bh, Z, R);
  gru_persist<<<NWGP, 256, 155648, stream>>>(Wzh, Whh, H, Z, R, h_buf, ghb, ctrs);
}